// Round 12
// baseline (85.421 us; speedup 1.0000x reference)
//
#include <hip/hip_runtime.h>
#include <hip/hip_bf16.h>

// Problem constants
#define B_    8
#define Qn    16
#define S_    4096
#define Hh    32
#define KVH_  8
#define D_    128
#define G_    4
#define ROWS  64          // G_*Qn score rows per (b,kvh)
#define KT    32          // tokens per inner tile
#define NT_TOT (S_ / KT)  // 128 tiles across the sequence
#define THREADS 256
#define VTS   40          // vt row stride (shorts): 80B, 16B-aligned reads

typedef unsigned int u32;
typedef unsigned short u16;
typedef __attribute__((ext_vector_type(8))) short short8;   // 8 bf16 (4 VGPRs)
typedef __attribute__((ext_vector_type(4))) float f32x4;    // MFMA C/D

__device__ __forceinline__ u16 f2bf(float f){
  union{u32 u; float f;} t; t.f = f; u32 u = t.u;
  return (u16)((u + 0x7fffu + ((u >> 16) & 1u)) >> 16);   // RNE
}
__device__ __forceinline__ float bf2f(u16 h){
  union{u32 x; float f;} t; t.x = ((u32)h) << 16; return t.f;
}
// Quantize to signed nibble value held as bf16 (ints in [-7,7] exact, see R2).
__device__ __forceinline__ u16 qnib(float x, float inv){
  union{float f; u32 u;} t; t.f = rintf(x * inv);
  return (u16)(t.u >> 16);
}

// Async global->LDS DMA: no result register, tracked by vmcnt, NOT drained by
// raw s_barrier. LDS dest = wave-uniform base + lane*16 (linear).
__device__ __forceinline__ void gll16(const float* g, const void* lds){
  __builtin_amdgcn_global_load_lds((const __attribute__((address_space(1))) void*)g,
                                   (__attribute__((address_space(3))) void*)lds,
                                   16, 0, 0);
}
#define SBAR0 __builtin_amdgcn_sched_barrier(0)

// attn_partial: grid (nchunk, KVH_, B_) x 256 threads, 4 blocks/CU (LDS 34.3KB).
// Split-phase pipeline over ONE 16KB raw buffer (wave-local refills):
//   [vmcnt(0): K_t landed] read own K->regs, lgkm, REFILL raw with V_t (own
//   region), quant K->kn, [lgkm+bar1], QK^T + softmax-part-1 (kscale only),
//   [vmcnt(0): V_t landed] read own V->regs, lgkm, REFILL raw with K_{t+1},
//   quant V->vt, [lgkm+bar2], P~ pack (vscale) + transpose + PV.
// Every DMA batch is issued ~half an iteration before its wait and crosses a
// barrier in flight (counted-vmcnt, T3/T4). Raw buffer hazards are wave-local
// only: wave w's gll targets exactly the bytes wave w itself just read.
__global__ __launch_bounds__(THREADS)
__attribute__((amdgpu_waves_per_eu(4)))
void attn_partial(const float* __restrict__ q, const float* __restrict__ k,
                  const float* __restrict__ v, float* __restrict__ part_o,
                  float* __restrict__ part_ml, int nchunk)
{
  __shared__ __attribute__((aligned(16))) float raw[KT * D_];  // 16 KB K/V alternating
  __shared__ u16   kn[KT * D_];     // 8 KB quantized K, granule-swizzled
  __shared__ u16   vt[D_ * VTS];    // 10 KB quantized V^T, padded rows
  __shared__ float ksc[KT];
  __shared__ float vsc[KT];

  const int chunk = blockIdx.x;
  const int kvh   = blockIdx.y;
  const int b     = blockIdx.z;
  const int tid   = threadIdx.x;
  const int lane  = tid & 63;
  const int w     = tid >> 6;                  // wave id == head group g
  const int l15   = lane & 15;
  const int l4    = lane >> 4;                 // 0..3
  const int t0    = (chunk * NT_TOT) / nchunk;
  const int t1    = ((chunk + 1) * NT_TOT) / nchunk;
  const float RS = 0.08838834764831844f;       // 1/sqrt(128)

  // quant-phase assignment: thread <-> OWN wave's staged token lt
  const int lt  = tid >> 3;                    // token 0..31 (= 8w + (lane>>3))
  const int qd4 = (tid & 7) * 4;

  // ---- Q fragments (hi/lo bf16 split) straight into registers ----
  short8 qhi[4], qlo[4];
  {
    const int h = kvh * G_ + w;
    const float* qp = q + (((size_t)(b * Qn + l15) * Hh) + h) * (size_t)D_ + (l4 * 8);
    #pragma unroll
    for (int kc = 0; kc < 4; ++kc){
      const float4 a = *(const float4*)(qp + kc * 32);
      const float4 c = *(const float4*)(qp + kc * 32 + 4);
      const float fv[8] = {a.x, a.y, a.z, a.w, c.x, c.y, c.z, c.w};
      #pragma unroll
      for (int i = 0; i < 8; ++i){
        const u16 hi = f2bf(fv[i]);
        qhi[kc][i] = (short)hi;
        qlo[kc][i] = (short)f2bf(fv[i] - bf2f(hi));
      }
    }
  }

  float m_i = -1e30f, l_i = 0.f;               // per-lane, qi = l15 view
  f32x4 acc_o[8];                              // O: col d = df*16+l15, row qi = l4*4+reg
  #pragma unroll
  for (int df = 0; df < 8; ++df) acc_o[df] = (f32x4)0.f;

  // gll mapping (linear): issue j covers granules (w*4+j)*64 + lane,
  // i.e. wave w stages tokens 8w..8w+7 into raw[8w*128 .. ].
  const int lhi = lane >> 5, cp = lane & 31;
  int goff[4];
  #pragma unroll
  for (int j = 0; j < 4; ++j){
    const int tokp = (w * 4 + j) * 2 + lhi;
    goff[j] = tokp * (KVH_ * D_) + (cp << 2);
  }
  const size_t tb0 = ((size_t)b * S_) * KVH_ * D_ + (size_t)kvh * D_;
  const char* rawb = (const char*)raw;

  // ---- prologue: issue async staging of K(t0) ----
  {
    const size_t base = tb0 + (size_t)(t0 * KT) * KVH_ * D_;
    #pragma unroll
    for (int j = 0; j < 4; ++j) gll16(k + base + goff[j], rawb + (w * 4 + j) * 1024);
  }

  for (int t = t0; t < t1; ++t){
    const int s0 = t * KT;
    const size_t base_t = tb0 + (size_t)s0 * KVH_ * D_;

    // ---- K_t landed (own wave's 4 glls) ----
    asm volatile("s_waitcnt vmcnt(0)" ::: "memory"); SBAR0;
    float4 kr[4];
    #pragma unroll
    for (int m = 0; m < 4; ++m)
      kr[m] = *(const float4*)(raw + lt * D_ + qd4 + m * 32);
    asm volatile("s_waitcnt lgkmcnt(0)" ::: "memory"); SBAR0;

    // ---- refill own raw region with V_t (flies across bar1 + QK + softmax) ----
    #pragma unroll
    for (int j = 0; j < 4; ++j) gll16(v + base_t + goff[j], rawb + (w * 4 + j) * 1024);
    SBAR0;

    // ---- quant K -> kn (swizzled) + kscale ----
    {
      float am = 0.f;
      #pragma unroll
      for (int m = 0; m < 4; ++m)
        am = fmaxf(am, fmaxf(fmaxf(fabsf(kr[m].x), fabsf(kr[m].y)),
                             fmaxf(fabsf(kr[m].z), fabsf(kr[m].w))));
      am = fmaxf(am, __shfl_xor(am, 1));
      am = fmaxf(am, __shfl_xor(am, 2));
      am = fmaxf(am, __shfl_xor(am, 4));
      const float sc = fmaxf(am * (1.f / 7.f), 1e-8f);
      if ((tid & 7) == 0) ksc[lt] = sc;
      const float inv = 1.f / sc;
      #pragma unroll
      for (int m = 0; m < 4; ++m){
        const int d0 = qd4 + m * 32;
        const int idx = lt * D_ + ((((d0 >> 3) ^ (lt & 7)) << 3) | (d0 & 7));
        *(ushort4*)&kn[idx] = make_ushort4(qnib(kr[m].x, inv), qnib(kr[m].y, inv),
                                           qnib(kr[m].z, inv), qnib(kr[m].w, inv));
      }
    }
    asm volatile("s_waitcnt lgkmcnt(0)" ::: "memory"); SBAR0;
    __builtin_amdgcn_s_barrier();                      // bar1: kn + ksc visible
    SBAR0;

    // ---- QK^T (swapped): st[cf] C[tok=l4*4+r+16cf][qi=l15] ----
    f32x4 st[2];
    st[0] = (f32x4)0.f; st[1] = (f32x4)0.f;
    __builtin_amdgcn_s_setprio(1);
    #pragma unroll
    for (int kc = 0; kc < 4; ++kc){
      #pragma unroll
      for (int cf = 0; cf < 2; ++cf){
        const int tok = cf * 16 + l15;
        const int gr  = kc * 4 + l4;           // d-granule 0..15
        const short8 kf = *(const short8*)&kn[tok * D_ + ((gr ^ (tok & 7)) << 3)];
        st[cf] = __builtin_amdgcn_mfma_f32_16x16x32_bf16(kf, qhi[kc], st[cf], 0, 0, 0);
        st[cf] = __builtin_amdgcn_mfma_f32_16x16x32_bf16(kf, qlo[kc], st[cf], 0, 0, 0);
      }
    }
    __builtin_amdgcn_s_setprio(0);

    // ---- softmax part 1 (needs kscale only; vscale deferred) ----
    float ksr[2][4];
    #pragma unroll
    for (int cf = 0; cf < 2; ++cf){
      const float4 ks = *(const float4*)&ksc[cf * 16 + l4 * 4];
      ksr[cf][0] = ks.x * RS; ksr[cf][1] = ks.y * RS;
      ksr[cf][2] = ks.z * RS; ksr[cf][3] = ks.w * RS;
    }
    const bool need_mask = (s0 + KT > S_ - Qn);      // only the last tile
    float x[2][4]; float rm = -1e30f;
    #pragma unroll
    for (int cf = 0; cf < 2; ++cf)
      #pragma unroll
      for (int r = 0; r < 4; ++r){
        float xx = st[cf][r] * ksr[cf][r];
        if (need_mask && (s0 + cf * 16 + l4 * 4 + r > S_ - Qn + l15)) xx = -1e30f;
        x[cf][r] = xx; rm = fmaxf(rm, xx);
      }
    rm = fmaxf(rm, __shfl_xor(rm, 16));
    rm = fmaxf(rm, __shfl_xor(rm, 32));
    const float mn  = fmaxf(m_i, rm);
    const float fac = __expf(m_i - mn);
    m_i = mn;
    float p[2][4]; float rs = 0.f;
    #pragma unroll
    for (int cf = 0; cf < 2; ++cf)
      #pragma unroll
      for (int r = 0; r < 4; ++r){
        p[cf][r] = __expf(x[cf][r] - mn);
        rs += p[cf][r];
      }
    rs += __shfl_xor(rs, 16);
    rs += __shfl_xor(rs, 32);
    l_i = l_i * fac + rs;
    // rescale acc_o now (only needs fac)
    f32x4 facv;
    #pragma unroll
    for (int r = 0; r < 4; ++r) facv[r] = __shfl(fac, l4 * 4 + r);
    #pragma unroll
    for (int df = 0; df < 8; ++df) acc_o[df] *= facv;

    // ---- V_t landed (own wave) ----
    asm volatile("s_waitcnt vmcnt(0)" ::: "memory"); SBAR0;
    float4 vr[4];
    #pragma unroll
    for (int m = 0; m < 4; ++m)
      vr[m] = *(const float4*)(raw + lt * D_ + qd4 + m * 32);
    asm volatile("s_waitcnt lgkmcnt(0)" ::: "memory"); SBAR0;

    // ---- refill own raw region with K_{t+1} (flies across bar2 + PV + top) ----
    if (t + 1 < t1){
      const size_t base_n = base_t + (size_t)KT * KVH_ * D_;
      #pragma unroll
      for (int j = 0; j < 4; ++j) gll16(k + base_n + goff[j], rawb + (w * 4 + j) * 1024);
    }
    SBAR0;

    // ---- quant V -> vt (transposed, padded rows) + vscale ----
    {
      float am = 0.f;
      #pragma unroll
      for (int m = 0; m < 4; ++m)
        am = fmaxf(am, fmaxf(fmaxf(fabsf(vr[m].x), fabsf(vr[m].y)),
                             fmaxf(fabsf(vr[m].z), fabsf(vr[m].w))));
      am = fmaxf(am, __shfl_xor(am, 1));
      am = fmaxf(am, __shfl_xor(am, 2));
      am = fmaxf(am, __shfl_xor(am, 4));
      const float sc = fmaxf(am * (1.f / 7.f), 1e-8f);
      if ((tid & 7) == 0) vsc[lt] = sc;
      const float inv = 1.f / sc;
      #pragma unroll
      for (int m = 0; m < 4; ++m){
        const int d0 = qd4 + m * 32;
        vt[(d0 + 0) * VTS + lt] = qnib(vr[m].x, inv);
        vt[(d0 + 1) * VTS + lt] = qnib(vr[m].y, inv);
        vt[(d0 + 2) * VTS + lt] = qnib(vr[m].z, inv);
        vt[(d0 + 3) * VTS + lt] = qnib(vr[m].w, inv);
      }
    }
    asm volatile("s_waitcnt lgkmcnt(0)" ::: "memory"); SBAR0;
    __builtin_amdgcn_s_barrier();                      // bar2: vt + vsc visible
    SBAR0;

    // ---- P~ pack with vscale + 8-shfl transpose to PV A-frag ----
    float vsv[2][4];
    #pragma unroll
    for (int cf = 0; cf < 2; ++cf){
      const float4 vs = *(const float4*)&vsc[cf * 16 + l4 * 4];
      vsv[cf][0] = vs.x; vsv[cf][1] = vs.y; vsv[cf][2] = vs.z; vsv[cf][3] = vs.w;
    }
    u32 pk0[2], pk1[2];
    #pragma unroll
    for (int rp = 0; rp < 2; ++rp){
      pk0[rp] = (u32)f2bf(p[0][2*rp] * vsv[0][2*rp]) | ((u32)f2bf(p[0][2*rp+1] * vsv[0][2*rp+1]) << 16);
      pk1[rp] = (u32)f2bf(p[1][2*rp] * vsv[1][2*rp]) | ((u32)f2bf(p[1][2*rp+1] * vsv[1][2*rp+1]) << 16);
    }
    const int s0L = ((l4 & 1) * 2) * 16 + l15;
    const int s1L = s0L + 16;
    const u32 a00 = __shfl((int)pk0[0], s0L), a01 = __shfl((int)pk0[1], s0L);
    const u32 a02 = __shfl((int)pk0[0], s1L), a03 = __shfl((int)pk0[1], s1L);
    const u32 a10 = __shfl((int)pk1[0], s0L), a11 = __shfl((int)pk1[1], s0L);
    const u32 a12 = __shfl((int)pk1[0], s1L), a13 = __shfl((int)pk1[1], s1L);
    const bool hi = (l4 >= 2);
    union { uint4 u; short8 s; } pfu;
    pfu.u = make_uint4(hi ? a10 : a00, hi ? a11 : a01,
                       hi ? a12 : a02, hi ? a13 : a03);
    const short8 pf = pfu.s;

    // ---- PV via MFMA: A = P~ (in-register), B = V^T tile ----
    __builtin_amdgcn_s_setprio(1);
    #pragma unroll
    for (int df = 0; df < 8; ++df){
      const int d = df * 16 + l15;
      const short8 vf = *(const short8*)&vt[d * VTS + l4 * 8];
      acc_o[df] = __builtin_amdgcn_mfma_f32_16x16x32_bf16(pf, vf, acc_o[df], 0, 0, 0);
    }
    __builtin_amdgcn_s_setprio(0);
    // no end barrier: vt/kn rewrites gated by next iter's bar1/bar2; raw
    // refills are wave-local.
  }

  asm volatile("s_waitcnt vmcnt(0)" ::: "memory"); SBAR0; // drain (no-op normally)

  // ---- write partials (unnormalized O, m, l) ----
  {
    const size_t base = (((size_t)b * KVH_ + kvh) * (size_t)nchunk + chunk) * ROWS;
    #pragma unroll
    for (int r = 0; r < 4; ++r){
      const int qrow = (w << 4) + (l4 << 2) + r;
      #pragma unroll
      for (int df = 0; df < 8; ++df)
        part_o[(base + qrow) * D_ + df * 16 + l15] = acc_o[df][r];
    }
    if (l4 == 0){                              // lanes 0..15 hold qi=l15 state
      part_ml[(base + (w << 4) + l15) * 2 + 0] = m_i;
      part_ml[(base + (w << 4) + l15) * 2 + 1] = l_i;
    }
  }
}

__global__ void attn_reduce(const float* __restrict__ part_o, const float* __restrict__ part_ml,
                            float* __restrict__ out, int nchunk)
{
  const int row = blockIdx.x;   // 0..63  (= g*16 + qi)
  const int kvh = blockIdx.y;
  const int b   = blockIdx.z;
  const int d   = threadIdx.x;  // 0..127
  const size_t base = ((size_t)b * KVH_ + kvh) * (size_t)nchunk;

  float M = -1e30f;
  for (int c = 0; c < nchunk; ++c)
    M = fmaxf(M, part_ml[((base + c) * ROWS + row) * 2 + 0]);
  float acc = 0.f, lt = 0.f;
  #pragma unroll 4
  for (int c = 0; c < nchunk; ++c){
    const float m = part_ml[((base + c) * ROWS + row) * 2 + 0];
    const float l = part_ml[((base + c) * ROWS + row) * 2 + 1];
    const float w = __expf(m - M);
    lt += w * l;
    acc += w * part_o[((base + c) * ROWS + row) * D_ + d];
  }
  const int g = row >> 4, qi = row & 15;
  out[(((size_t)b * Qn + qi) * Hh + kvh * G_ + g) * (size_t)D_ + d] = acc / lt;
}

extern "C" void kernel_launch(void* const* d_in, const int* in_sizes, int n_in,
                              void* d_out, int out_size, void* d_ws, size_t ws_size,
                              hipStream_t stream)
{
  const float* q = (const float*)d_in[0];
  const float* k = (const float*)d_in[1];
  const float* v = (const float*)d_in[2];
  // d_in[3] = block_table: identity permutation round-trip; ECC encode/decode
  // with no injected errors is the identity on the nibble -> fake-quant only.
  float* out = (float*)d_out;

  // nchunk=16 -> 1024 blocks = 4 blocks/CU (LDS 34.3 KB), zero tail.
  int nchunk = 16;
  while (nchunk > 4 &&
         ((size_t)B_ * KVH_ * nchunk * ROWS * (D_ + 2) * 4ull) > ws_size)
    nchunk >>= 1;

  float* part_o  = (float*)d_ws;
  float* part_ml = part_o + (size_t)B_ * KVH_ * nchunk * ROWS * D_;

  attn_partial<<<dim3(nchunk, KVH_, B_), THREADS, 0, stream>>>(q, k, v, part_o, part_ml, nchunk);
  attn_reduce<<<dim3(ROWS, KVH_, B_), 128, 0, stream>>>(part_o, part_ml, out, nchunk);
}

// Round 13
// 63.650 us; speedup vs baseline: 1.3420x; 1.3420x over previous
//
#include <hip/hip_runtime.h>
#include <hip/hip_bf16.h>

// Problem constants
#define B_    8
#define Qn    16
#define S_    4096
#define Hh    32
#define KVH_  8
#define D_    128
#define G_    4
#define ROWS  64          // G_*Qn score rows per (b,kvh)
#define KT    32          // tokens per inner tile
#define NT_TOT (S_ / KT)  // 128 tiles across the sequence
#define NCHUNK 12         // 768 blocks = 256 CU x 3 resident (LDS 50.5 KB)
#define THREADS 256
#define VTS   40          // vt row stride (shorts): 80B, 16B-aligned reads

typedef unsigned int u32;
typedef unsigned short u16;
typedef __attribute__((ext_vector_type(8))) short short8;   // 8 bf16 (4 VGPRs)
typedef __attribute__((ext_vector_type(4))) float f32x4;    // MFMA C/D

__device__ __forceinline__ u16 f2bf(float f){
  union{u32 u; float f;} t; t.f = f; u32 u = t.u;
  return (u16)((u + 0x7fffu + ((u >> 16) & 1u)) >> 16);   // RNE
}
__device__ __forceinline__ float bf2f(u16 h){
  union{u32 x; float f;} t; t.x = ((u32)h) << 16; return t.f;
}
// Quantize to signed nibble value held as bf16 (ints in [-7,7] exact, see R2).
__device__ __forceinline__ u16 qnib(float x, float inv){
  union{float f; u32 u;} t; t.f = rintf(x * inv);
  return (u16)(t.u >> 16);
}

// Async global->LDS DMA: no result register, tracked by vmcnt, NOT drained by
// raw s_barrier. LDS dest = wave-uniform base + lane*16 (linear).
__device__ __forceinline__ void gll16(const float* g, const void* lds){
  __builtin_amdgcn_global_load_lds((const __attribute__((address_space(1))) void*)g,
                                   (__attribute__((address_space(3))) void*)lds,
                                   16, 0, 0);
}
#define SBAR0 __builtin_amdgcn_sched_barrier(0)

// attn_partial: grid (KVH_, NCHUNK, B_) x 256 threads, 3 blocks/CU.
// kvh is the FASTEST grid dim: the 8 blocks covering the 8 kvh slices of the
// same (b, chunk) are dispatched adjacently, so their 512B-of-every-4KB
// strided reads interleave into dense DRAM row coverage.
// Pipeline (never drains vmcnt below 4 in the loop):
//   bar1 [prev compute reads done]
//   vmcnt(4): K_t landed (V_t flying) -> read own K->regs -> lgkm ->
//   issue gll K(t+1) into own rawK region -> quant K->kn
//   vmcnt(4): V_t landed (K(t+1) flying) -> read own V->regs -> lgkm ->
//   issue gll V(t+1) -> quant V->vt -> lgkm -> bar2 -> QK/softmax/PV.
// Raw-region hazards are wave-local (wave w stages and reads tokens 8w..8w+7).
__global__ __launch_bounds__(THREADS)
__attribute__((amdgpu_waves_per_eu(3)))
void attn_partial(const float* __restrict__ q, const float* __restrict__ k,
                  const float* __restrict__ v, float* __restrict__ part_o,
                  float* __restrict__ part_ml)
{
  __shared__ __attribute__((aligned(16))) float rawK[KT * D_];  // 16 KB
  __shared__ __attribute__((aligned(16))) float rawV[KT * D_];  // 16 KB
  __shared__ u16   kn[KT * D_];     // 8 KB quantized K, granule-swizzled
  __shared__ u16   vt[D_ * VTS];    // 10 KB quantized V^T, padded rows
  __shared__ float ksc[KT];
  __shared__ float vsc[KT];

  const int kvh   = blockIdx.x;                // fastest: DRAM-dense grouping
  const int chunk = blockIdx.y;
  const int b     = blockIdx.z;
  const int tid   = threadIdx.x;
  const int lane  = tid & 63;
  const int w     = tid >> 6;                  // wave id == head group g
  const int l15   = lane & 15;
  const int l4    = lane >> 4;                 // 0..3
  const int t0    = (chunk * NT_TOT) / NCHUNK;
  const int t1    = ((chunk + 1) * NT_TOT) / NCHUNK;
  const float RS = 0.08838834764831844f;       // 1/sqrt(128)

  // quant-phase assignment: thread <-> OWN wave's staged token lt
  const int lt  = tid >> 3;                    // token 0..31 (= 8w + (lane>>3))
  const int qd4 = (tid & 7) * 4;

  // ---- Q fragments (hi/lo bf16 split) straight into registers ----
  short8 qhi[4], qlo[4];
  {
    const int h = kvh * G_ + w;
    const float* qp = q + (((size_t)(b * Qn + l15) * Hh) + h) * (size_t)D_ + (l4 * 8);
    #pragma unroll
    for (int kc = 0; kc < 4; ++kc){
      const float4 a = *(const float4*)(qp + kc * 32);
      const float4 c = *(const float4*)(qp + kc * 32 + 4);
      const float fv[8] = {a.x, a.y, a.z, a.w, c.x, c.y, c.z, c.w};
      #pragma unroll
      for (int i = 0; i < 8; ++i){
        const u16 hi = f2bf(fv[i]);
        qhi[kc][i] = (short)hi;
        qlo[kc][i] = (short)f2bf(fv[i] - bf2f(hi));
      }
    }
  }

  float m_i = -1e30f, l_i = 0.f;               // per-lane, qi = l15 view
  f32x4 acc_o[8];                              // O: col d = df*16+l15, row qi = l4*4+reg
  #pragma unroll
  for (int df = 0; df < 8; ++df) acc_o[df] = (f32x4)0.f;

  // gll mapping (linear): issue j covers granules (w*4+j)*64 + lane,
  // i.e. wave w stages tokens 8w..8w+7 (its own quant tokens).
  const int lhi = lane >> 5, cp = lane & 31;
  int goff[4];
  #pragma unroll
  for (int j = 0; j < 4; ++j){
    const int tokp = (w * 4 + j) * 2 + lhi;
    goff[j] = tokp * (KVH_ * D_) + (cp << 2);
  }
  const size_t tb0 = ((size_t)b * S_) * KVH_ * D_ + (size_t)kvh * D_;
  const char* rawKb = (const char*)rawK;
  const char* rawVb = (const char*)rawV;

  // ---- prologue: issue async staging of tile t0 (K first, then V) ----
  {
    const size_t base = tb0 + (size_t)(t0 * KT) * KVH_ * D_;
    #pragma unroll
    for (int j = 0; j < 4; ++j) gll16(k + base + goff[j], rawKb + (w * 4 + j) * 1024);
    #pragma unroll
    for (int j = 0; j < 4; ++j) gll16(v + base + goff[j], rawVb + (w * 4 + j) * 1024);
  }

  for (int t = t0; t < t1; ++t){
    const int s0 = t * KT;
    const int sn = (s0 + KT <= S_ - KT) ? (s0 + KT) : (S_ - KT);  // clamped t+1
    const size_t base_n = tb0 + (size_t)sn * KVH_ * D_;

    __builtin_amdgcn_s_barrier();                      // bar1: prev reads done
    SBAR0;

    // ---- K_t landed (oldest 4 of this wave's 8 glls); V_t still flying ----
    asm volatile("s_waitcnt vmcnt(4)" ::: "memory"); SBAR0;
    float4 kr[4];
    #pragma unroll
    for (int m = 0; m < 4; ++m)
      kr[m] = *(const float4*)(rawK + lt * D_ + qd4 + m * 32);
    asm volatile("s_waitcnt lgkmcnt(0)" ::: "memory"); SBAR0;

    // ---- own rawK region free -> issue K(t+1) (flies across everything) ----
    #pragma unroll
    for (int j = 0; j < 4; ++j) gll16(k + base_n + goff[j], rawKb + (w * 4 + j) * 1024);
    SBAR0;

    // ---- quant K -> kn (swizzled) + kscale (V_t delivery hides under this) ----
    {
      float am = 0.f;
      #pragma unroll
      for (int m = 0; m < 4; ++m)
        am = fmaxf(am, fmaxf(fmaxf(fabsf(kr[m].x), fabsf(kr[m].y)),
                             fmaxf(fabsf(kr[m].z), fabsf(kr[m].w))));
      am = fmaxf(am, __shfl_xor(am, 1));
      am = fmaxf(am, __shfl_xor(am, 2));
      am = fmaxf(am, __shfl_xor(am, 4));
      const float sc = fmaxf(am * (1.f / 7.f), 1e-8f);
      if ((tid & 7) == 0) ksc[lt] = sc;
      const float inv = 1.f / sc;
      #pragma unroll
      for (int m = 0; m < 4; ++m){
        const int d0 = qd4 + m * 32;
        const int idx = lt * D_ + ((((d0 >> 3) ^ (lt & 7)) << 3) | (d0 & 7));
        *(ushort4*)&kn[idx] = make_ushort4(qnib(kr[m].x, inv), qnib(kr[m].y, inv),
                                           qnib(kr[m].z, inv), qnib(kr[m].w, inv));
      }
    }

    // ---- V_t landed (K(t+1) flying) ----
    asm volatile("s_waitcnt vmcnt(4)" ::: "memory"); SBAR0;
    float4 vr[4];
    #pragma unroll
    for (int m = 0; m < 4; ++m)
      vr[m] = *(const float4*)(rawV + lt * D_ + qd4 + m * 32);
    asm volatile("s_waitcnt lgkmcnt(0)" ::: "memory"); SBAR0;

    // ---- own rawV region free -> issue V(t+1) ----
    #pragma unroll
    for (int j = 0; j < 4; ++j) gll16(v + base_n + goff[j], rawVb + (w * 4 + j) * 1024);
    SBAR0;

    // ---- quant V -> vt (transposed, padded rows) + vscale ----
    {
      float am = 0.f;
      #pragma unroll
      for (int m = 0; m < 4; ++m)
        am = fmaxf(am, fmaxf(fmaxf(fabsf(vr[m].x), fabsf(vr[m].y)),
                             fmaxf(fabsf(vr[m].z), fabsf(vr[m].w))));
      am = fmaxf(am, __shfl_xor(am, 1));
      am = fmaxf(am, __shfl_xor(am, 2));
      am = fmaxf(am, __shfl_xor(am, 4));
      const float sc = fmaxf(am * (1.f / 7.f), 1e-8f);
      if ((tid & 7) == 0) vsc[lt] = sc;
      const float inv = 1.f / sc;
      #pragma unroll
      for (int m = 0; m < 4; ++m){
        const int d0 = qd4 + m * 32;
        vt[(d0 + 0) * VTS + lt] = qnib(vr[m].x, inv);
        vt[(d0 + 1) * VTS + lt] = qnib(vr[m].y, inv);
        vt[(d0 + 2) * VTS + lt] = qnib(vr[m].z, inv);
        vt[(d0 + 3) * VTS + lt] = qnib(vr[m].w, inv);
      }
    }
    asm volatile("s_waitcnt lgkmcnt(0)" ::: "memory"); SBAR0;
    __builtin_amdgcn_s_barrier();                      // bar2: kn/vt/scales visible
    SBAR0;

    // ---- QK^T (swapped): st[cf] C[tok=l4*4+r+16cf][qi=l15] ----
    f32x4 st[2];
    st[0] = (f32x4)0.f; st[1] = (f32x4)0.f;
    __builtin_amdgcn_s_setprio(1);
    #pragma unroll
    for (int kc = 0; kc < 4; ++kc){
      #pragma unroll
      for (int cf = 0; cf < 2; ++cf){
        const int tok = cf * 16 + l15;
        const int gr  = kc * 4 + l4;           // d-granule 0..15
        const short8 kf = *(const short8*)&kn[tok * D_ + ((gr ^ (tok & 7)) << 3)];
        st[cf] = __builtin_amdgcn_mfma_f32_16x16x32_bf16(kf, qhi[kc], st[cf], 0, 0, 0);
        st[cf] = __builtin_amdgcn_mfma_f32_16x16x32_bf16(kf, qlo[kc], st[cf], 0, 0, 0);
      }
    }
    __builtin_amdgcn_s_setprio(0);

    // ---- online softmax in [tok][qi] layout (R7-verified) ----
    float ksr[2][4], vsv[2][4];
    #pragma unroll
    for (int cf = 0; cf < 2; ++cf){
      const float4 ks = *(const float4*)&ksc[cf * 16 + l4 * 4];
      const float4 vs = *(const float4*)&vsc[cf * 16 + l4 * 4];
      ksr[cf][0] = ks.x * RS; ksr[cf][1] = ks.y * RS;
      ksr[cf][2] = ks.z * RS; ksr[cf][3] = ks.w * RS;
      vsv[cf][0] = vs.x; vsv[cf][1] = vs.y; vsv[cf][2] = vs.z; vsv[cf][3] = vs.w;
    }
    const bool need_mask = (s0 + KT > S_ - Qn);      // only the last tile
    float x[2][4]; float rm = -1e30f;
    #pragma unroll
    for (int cf = 0; cf < 2; ++cf)
      #pragma unroll
      for (int r = 0; r < 4; ++r){
        float xx = st[cf][r] * ksr[cf][r];
        if (need_mask && (s0 + cf * 16 + l4 * 4 + r > S_ - Qn + l15)) xx = -1e30f;
        x[cf][r] = xx; rm = fmaxf(rm, xx);
      }
    rm = fmaxf(rm, __shfl_xor(rm, 16));
    rm = fmaxf(rm, __shfl_xor(rm, 32));
    const float mn  = fmaxf(m_i, rm);
    const float fac = __expf(m_i - mn);
    m_i = mn;
    float p[2][4]; float rs = 0.f;
    #pragma unroll
    for (int cf = 0; cf < 2; ++cf)
      #pragma unroll
      for (int r = 0; r < 4; ++r){
        p[cf][r] = __expf(x[cf][r] - mn);
        rs += p[cf][r];
      }
    rs += __shfl_xor(rs, 16);
    rs += __shfl_xor(rs, 32);
    l_i = l_i * fac + rs;

    // P~ = bf16(p * vscale[tok]) packed, then 8-shfl transpose to PV A-frag
    u32 pk0[2], pk1[2];
    #pragma unroll
    for (int rp = 0; rp < 2; ++rp){
      pk0[rp] = (u32)f2bf(p[0][2*rp] * vsv[0][2*rp]) | ((u32)f2bf(p[0][2*rp+1] * vsv[0][2*rp+1]) << 16);
      pk1[rp] = (u32)f2bf(p[1][2*rp] * vsv[1][2*rp]) | ((u32)f2bf(p[1][2*rp+1] * vsv[1][2*rp+1]) << 16);
    }
    const int s0L = ((l4 & 1) * 2) * 16 + l15;
    const int s1L = s0L + 16;
    const u32 a00 = __shfl((int)pk0[0], s0L), a01 = __shfl((int)pk0[1], s0L);
    const u32 a02 = __shfl((int)pk0[0], s1L), a03 = __shfl((int)pk0[1], s1L);
    const u32 a10 = __shfl((int)pk1[0], s0L), a11 = __shfl((int)pk1[1], s0L);
    const u32 a12 = __shfl((int)pk1[0], s1L), a13 = __shfl((int)pk1[1], s1L);
    const bool hi = (l4 >= 2);
    union { uint4 u; short8 s; } pfu;
    pfu.u = make_uint4(hi ? a10 : a00, hi ? a11 : a01,
                       hi ? a12 : a02, hi ? a13 : a03);
    const short8 pf = pfu.s;

    f32x4 facv;
    #pragma unroll
    for (int r = 0; r < 4; ++r) facv[r] = __shfl(fac, l4 * 4 + r);
    #pragma unroll
    for (int df = 0; df < 8; ++df) acc_o[df] *= facv;

    // ---- PV via MFMA: A = P~ (in-register), B = V^T tile ----
    __builtin_amdgcn_s_setprio(1);
    #pragma unroll
    for (int df = 0; df < 8; ++df){
      const int d = df * 16 + l15;
      const short8 vf = *(const short8*)&vt[d * VTS + l4 * 8];
      acc_o[df] = __builtin_amdgcn_mfma_f32_16x16x32_bf16(pf, vf, acc_o[df], 0, 0, 0);
    }
    __builtin_amdgcn_s_setprio(0);
    // no end barrier: kn/vt rewrites gated by next iter's bar1; raw refills
    // are wave-local.
  }

  asm volatile("s_waitcnt vmcnt(0)" ::: "memory"); SBAR0;  // drain dangling DMA

  // ---- write partials (unnormalized O, m, l) ----
  {
    const size_t base = (((size_t)b * KVH_ + kvh) * (size_t)NCHUNK + chunk) * ROWS;
    #pragma unroll
    for (int r = 0; r < 4; ++r){
      const int qrow = (w << 4) + (l4 << 2) + r;
      #pragma unroll
      for (int df = 0; df < 8; ++df)
        part_o[(base + qrow) * D_ + df * 16 + l15] = acc_o[df][r];
    }
    if (l4 == 0){                              // lanes 0..15 hold qi=l15 state
      part_ml[(base + (w << 4) + l15) * 2 + 0] = m_i;
      part_ml[(base + (w << 4) + l15) * 2 + 1] = l_i;
    }
  }
}

__global__ void attn_reduce(const float* __restrict__ part_o, const float* __restrict__ part_ml,
                            float* __restrict__ out)
{
  const int row = blockIdx.x;   // 0..63  (= g*16 + qi)
  const int kvh = blockIdx.y;
  const int b   = blockIdx.z;
  const int d   = threadIdx.x;  // 0..127
  const size_t base = ((size_t)b * KVH_ + kvh) * (size_t)NCHUNK;

  float M = -1e30f;
  for (int c = 0; c < NCHUNK; ++c)
    M = fmaxf(M, part_ml[((base + c) * ROWS + row) * 2 + 0]);
  float acc = 0.f, lt = 0.f;
  #pragma unroll
  for (int c = 0; c < NCHUNK; ++c){
    const float m = part_ml[((base + c) * ROWS + row) * 2 + 0];
    const float l = part_ml[((base + c) * ROWS + row) * 2 + 1];
    const float w = __expf(m - M);
    lt += w * l;
    acc += w * part_o[((base + c) * ROWS + row) * D_ + d];
  }
  const int g = row >> 4, qi = row & 15;
  out[(((size_t)b * Qn + qi) * Hh + kvh * G_ + g) * (size_t)D_ + d] = acc / lt;
}

extern "C" void kernel_launch(void* const* d_in, const int* in_sizes, int n_in,
                              void* d_out, int out_size, void* d_ws, size_t ws_size,
                              hipStream_t stream)
{
  const float* q = (const float*)d_in[0];
  const float* k = (const float*)d_in[1];
  const float* v = (const float*)d_in[2];
  // d_in[3] = block_table: identity permutation round-trip; ECC encode/decode
  // with no injected errors is the identity on the nibble -> fake-quant only.
  float* out = (float*)d_out;

  // part_o: B*KVH*NCHUNK*ROWS*D floats = 25.2 MB (fits d_ws as in R3-R11).
  float* part_o  = (float*)d_ws;
  float* part_ml = part_o + (size_t)B_ * KVH_ * NCHUNK * ROWS * D_;

  // kvh fastest -> the 8 kvh-slices of one (b,chunk) are co-dispatched and
  // together cover each 4KB K/V line densely (DRAM row locality).
  attn_partial<<<dim3(KVH_, NCHUNK, B_), THREADS, 0, stream>>>(q, k, v, part_o, part_ml);
  attn_reduce<<<dim3(ROWS, KVH_, B_), 128, 0, stream>>>(part_o, part_ml, out);
}